// Round 1
// baseline (2398.382 us; speedup 1.0000x reference)
//
#include <hip/hip_runtime.h>

#define NB 128
#define NP 576
#define NK 9
#define EMB 768
#define SGRID 24
#define COMPF 3.0f
#define NITER 10
#define EPSV 1e-8f
#define APAD 12

// ---------------- init centroids: SSN 3x3 pooling ----------------
__global__ __launch_bounds__(256) void init_cent(const float* __restrict__ emb,
                                                 float* __restrict__ cemb,
                                                 float* __restrict__ csp) {
    int b = blockIdx.x;
    int t = threadIdx.x;
    const float* e = emb + (size_t)b * NP * EMB;
    for (int k = 0; k < NK; ++k) {
        int ay = k / 3, cx = k % 3;
        for (int c = t; c < EMB; c += 256) {
            float s = 0.f;
            for (int iy = 0; iy < 8; ++iy) {
                int y = ay * 8 + iy;
                const float* row = e + (size_t)(y * SGRID + cx * 8) * EMB + c;
                #pragma unroll
                for (int ix = 0; ix < 8; ++ix) s += row[(size_t)ix * EMB];
            }
            cemb[((size_t)b * NK + k) * EMB + c] = s * (1.f / 64.f);
        }
    }
    if (t < NK) {
        int ay = t / 3, cx = t % 3;
        // exact mean of x*COMPF over 8x8 block = 3*(8*cx + 3.5)
        csp[((size_t)b * NK + t) * 2 + 0] = COMPF * (8.f * cx + 3.5f);
        csp[((size_t)b * NK + t) * 2 + 1] = COMPF * (8.f * ay + 3.5f);
    }
}

// ---------------- assign: softmax(2*pc - c2) ----------------
// grid = NB*9 blocks; each block does 64 points of one item.
// wave handles 4 points at a time; 16 lanes per point split the 768-dim dot.
__global__ __launch_bounds__(256) void assign_k(const float* __restrict__ emb,
                                                const float* __restrict__ cemb,
                                                const float* __restrict__ csp,
                                                float* __restrict__ out, int ostride) {
    __shared__ float4 sc[NK * 192];   // centroid emb, [9][192] float4
    __shared__ float ssp[NK * 2];
    __shared__ float sc2[NK];

    int blk = blockIdx.x;
    int b = blk / 9;
    int pb = blk % 9;
    int t = threadIdx.x;
    int lane = t & 63;
    int wv = t >> 6;

    const float4* cg = (const float4*)(cemb + (size_t)b * NK * EMB);
    for (int i = t; i < NK * 192; i += 256) sc[i] = cg[i];
    if (t < NK * 2) ssp[t] = csp[(size_t)b * NK * 2 + t];
    __syncthreads();

    if (wv == 0) {
        for (int k = 0; k < NK; ++k) {
            float s = 0.f;
            const float* ck = (const float*)(sc + k * 192);
            for (int c = lane; c < EMB; c += 64) { float v = ck[c]; s += v * v; }
            #pragma unroll
            for (int m = 1; m < 64; m <<= 1) s += __shfl_xor(s, m);
            if (lane == 0) {
                float cx = ssp[k * 2], cy = ssp[k * 2 + 1];
                sc2[k] = s + cx * cx + cy * cy;
            }
        }
    }
    __syncthreads();

    int sl = lane & 15;
    int pt = lane >> 4;
    for (int r = 0; r < 4; ++r) {
        int p = pb * 64 + wv * 16 + r * 4 + pt;
        const float4* ep = (const float4*)(emb + ((size_t)b * NP + p) * EMB);
        float4 ev[12];
        #pragma unroll
        for (int j = 0; j < 12; ++j) ev[j] = ep[sl + 16 * j];

        float logit[NK];
        #pragma unroll
        for (int k = 0; k < NK; ++k) {
            float acc = 0.f;
            const float4* ck = sc + k * 192;
            #pragma unroll
            for (int j = 0; j < 12; ++j) {
                float4 cv = ck[sl + 16 * j];
                acc += ev[j].x * cv.x + ev[j].y * cv.y + ev[j].z * cv.z + ev[j].w * cv.w;
            }
            acc += __shfl_xor(acc, 1);
            acc += __shfl_xor(acc, 2);
            acc += __shfl_xor(acc, 4);
            acc += __shfl_xor(acc, 8);
            logit[k] = acc;
        }
        float x = (float)(p % SGRID) * COMPF;
        float y = (float)(p / SGRID) * COMPF;
        float mx = -1e30f;
        #pragma unroll
        for (int k = 0; k < NK; ++k) {
            logit[k] = 2.f * (logit[k] + x * ssp[k * 2] + y * ssp[k * 2 + 1]) - sc2[k];
            mx = fmaxf(mx, logit[k]);
        }
        float se = 0.f;
        #pragma unroll
        for (int k = 0; k < NK; ++k) { logit[k] = __expf(logit[k] - mx); se += logit[k]; }
        float inv = 1.f / se;
        if (sl < NK) out[((size_t)b * NP + p) * ostride + sl] = logit[sl] * inv;
    }
}

// ---------------- update: new centroids ----------------
// grid = NB*3; each block does 256 emb channels of one item; block cb==0 also spatial.
__global__ __launch_bounds__(256) void update_k(const float* __restrict__ emb,
                                                const float* __restrict__ abuf,
                                                float* __restrict__ cemb,
                                                float* __restrict__ csp) {
    __shared__ float4 sa[NP * 3];     // a, [576][12] floats
    __shared__ float sw[NK];
    __shared__ float red[4 * NK];

    int b = blockIdx.x / 3;
    int cb = blockIdx.x % 3;
    int t = threadIdx.x;
    int lane = t & 63;
    int wv = t >> 6;

    const float4* ag = (const float4*)(abuf + (size_t)b * NP * APAD);
    for (int i = t; i < NP * 3; i += 256) sa[i] = ag[i];
    __syncthreads();

    // w[k] = sum_p a[p,k]
    float wp[NK];
    #pragma unroll
    for (int k = 0; k < NK; ++k) wp[k] = 0.f;
    for (int p = t; p < NP; p += 256) {
        const float* ar = (const float*)(sa + p * 3);
        #pragma unroll
        for (int k = 0; k < NK; ++k) wp[k] += ar[k];
    }
    #pragma unroll
    for (int k = 0; k < NK; ++k) {
        float s = wp[k];
        #pragma unroll
        for (int m = 1; m < 64; m <<= 1) s += __shfl_xor(s, m);
        if (lane == 0) red[wv * NK + k] = s;
    }
    __syncthreads();
    if (t < NK) sw[t] = red[t] + red[NK + t] + red[2 * NK + t] + red[3 * NK + t];
    __syncthreads();

    // main: acc[k] = sum_p a[p,k] * emb[p,c]
    int c = cb * 256 + t;
    float acc[NK];
    #pragma unroll
    for (int k = 0; k < NK; ++k) acc[k] = 0.f;
    const float* e = emb + (size_t)b * NP * EMB + c;
    #pragma unroll 2
    for (int p = 0; p < NP; ++p) {
        float fv = e[(size_t)p * EMB];
        const float* ar = (const float*)(sa + p * 3);
        #pragma unroll
        for (int k = 0; k < NK; ++k) acc[k] += ar[k] * fv;
    }
    float* co = cemb + (size_t)b * NK * EMB + c;
    #pragma unroll
    for (int k = 0; k < NK; ++k) co[(size_t)k * EMB] = acc[k] / (sw[k] + EPSV);

    // spatial centroids (one wave of block cb==0)
    if (cb == 0 && wv == 0) {
        for (int k = 0; k < NK; ++k) {
            float sx = 0.f, sy = 0.f;
            for (int p = lane; p < NP; p += 64) {
                float av = ((const float*)(sa + p * 3))[k];
                sx += av * (float)(p % SGRID) * COMPF;
                sy += av * (float)(p / SGRID) * COMPF;
            }
            #pragma unroll
            for (int m = 1; m < 64; m <<= 1) {
                sx += __shfl_xor(sx, m);
                sy += __shfl_xor(sy, m);
            }
            if (lane == 0) {
                float wk = sw[k] + EPSV;
                csp[((size_t)b * NK + k) * 2 + 0] = sx / wk;
                csp[((size_t)b * NK + k) * 2 + 1] = sy / wk;
            }
        }
    }
}

extern "C" void kernel_launch(void* const* d_in, const int* in_sizes, int n_in,
                              void* d_out, int out_size, void* d_ws, size_t ws_size,
                              hipStream_t stream) {
    const float* emb = (const float*)d_in[0];
    float* ws = (float*)d_ws;
    const size_t centEmbSz = (size_t)NB * NK * EMB;   // 884736
    const size_t centSpSz = (size_t)NB * NK * 2;      // 2304
    float* cA_emb = ws;
    float* cA_sp  = cA_emb + centEmbSz;
    float* cB_emb = cA_sp + centSpSz;
    float* cB_sp  = cB_emb + centEmbSz;
    float* abuf   = cB_sp + centSpSz;                 // NB*NP*APAD

    init_cent<<<NB, 256, 0, stream>>>(emb, cA_emb, cA_sp);

    float* ce = cA_emb; float* cs = cA_sp;
    float* ne = cB_emb; float* ns = cB_sp;
    for (int it = 0; it < NITER; ++it) {
        assign_k<<<NB * 9, 256, 0, stream>>>(emb, ce, cs, abuf, APAD);
        update_k<<<NB * 3, 256, 0, stream>>>(emb, abuf, ne, ns);
        float* te = ce; ce = ne; ne = te;
        float* ts = cs; cs = ns; ns = ts;
    }
    assign_k<<<NB * 9, 256, 0, stream>>>(emb, ce, cs, (float*)d_out, NK);
}

// Round 2
// 1025.770 us; speedup vs baseline: 2.3381x; 2.3381x over previous
//
#include <hip/hip_runtime.h>

#define NB 128
#define NP 576
#define NK 9
#define EMB 768
#define SGRID 24
#define COMPF 3.0f
#define NITER 10
#define EPSV 1e-8f
#define SUPD 12
#define PPB 48   // points per update block

typedef short v8s __attribute__((ext_vector_type(8)));
typedef float v4f __attribute__((ext_vector_type(4)));

__device__ __forceinline__ unsigned short f2b(float f) {
    unsigned x = __float_as_uint(f);
    unsigned r = (x + 0x7fffu + ((x >> 16) & 1u)) >> 16;
    return (unsigned short)r;
}
__device__ __forceinline__ float b2f(unsigned short u) {
    return __uint_as_float(((unsigned)u) << 16);
}

// ---------------- fp32 -> bf16 conversion of emb (once) ----------------
__global__ __launch_bounds__(256) void conv_k(const float* __restrict__ in,
                                              unsigned short* __restrict__ out) {
    size_t i = ((size_t)blockIdx.x * 256 + threadIdx.x) * 8;
    const float4* p = (const float4*)(in + i);
    float4 a = p[0], c = p[1];
    v8s o;
    o[0] = (short)f2b(a.x); o[1] = (short)f2b(a.y);
    o[2] = (short)f2b(a.z); o[3] = (short)f2b(a.w);
    o[4] = (short)f2b(c.x); o[5] = (short)f2b(c.y);
    o[6] = (short)f2b(c.z); o[7] = (short)f2b(c.w);
    *(v8s*)(out + i) = o;
}

// ---------------- assign via bf16 MFMA ----------------
// grid NB*9; block = 256 thr = 4 waves; wave w owns rows w*16..w*16+15 of its
// 64-row tile. K=768 in 12 chunks of 64, double-buffered LDS with XOR swizzle.
__global__ __launch_bounds__(256) void assign_mfma(
    const unsigned short* __restrict__ embb,   // [NB][576][768]
    const unsigned short* __restrict__ centb,  // [NB][9][768]
    const float* __restrict__ c2b,             // [NB][16] (k>=9 -> 1e30)
    const float* __restrict__ csp,             // [NB][9][2]
    float* __restrict__ out, int ostride)
{
    __shared__ unsigned short sc[16][776];     // B: [cluster][768 + pad8]
    __shared__ unsigned short sa[2][64][64];   // A dbuf: [row][64ch], slice-swizzled
    __shared__ float scx[16], scy[16], sc2[16];

    int blk = blockIdx.x;
    int b = blk / 9, pb = blk % 9;
    int t = threadIdx.x, lane = t & 63, wv = t >> 6;
    int r16 = lane & 15, g = lane >> 4;

    // stage centroids (B operand), zero-pad clusters 9..15
    const unsigned short* cg = centb + (size_t)b * NK * EMB;
    for (int i = t; i < NK * 96; i += 256) {
        int k = i / 96, s = i % 96;
        *(v8s*)&sc[k][s * 8] = *(const v8s*)&cg[k * EMB + s * 8];
    }
    for (int i = t; i < 7 * 96; i += 256) {
        int k = 9 + i / 96, s = i % 96;
        v8s z = {0,0,0,0,0,0,0,0};
        *(v8s*)&sc[k][s * 8] = z;
    }
    if (t < 16) {
        sc2[t] = c2b[b * 16 + t];
        scx[t] = (t < NK) ? csp[((size_t)b * NK + t) * 2 + 0] : 0.f;
        scy[t] = (t < NK) ? csp[((size_t)b * NK + t) * 2 + 1] : 0.f;
    }

    const unsigned short* eg = embb + ((size_t)b * NP + pb * 64) * EMB;
    int srow = wv * 16 + (lane >> 3);          // staging row (this wave's tile)
    int sphys = ((lane & 7) ^ (lane >> 3)) * 8; // swizzled slice slot (ushort idx)
    const unsigned short* gbase = eg + (size_t)srow * EMB + (lane & 7) * 8;

    v8s st0 = *(const v8s*)(gbase);
    v8s st1 = *(const v8s*)(gbase + 8 * EMB);
    *(v8s*)&sa[0][srow][sphys] = st0;
    *(v8s*)&sa[0][srow + 8][sphys] = st1;

    v4f acc = {0.f, 0.f, 0.f, 0.f};
    for (int cn = 0; cn < 12; ++cn) {
        v8s n0, n1;
        if (cn < 11) {
            n0 = *(const v8s*)(gbase + (cn + 1) * 64);
            n1 = *(const v8s*)(gbase + (cn + 1) * 64 + 8 * EMB);
        }
        __syncthreads();
        int cur = cn & 1;
        #pragma unroll
        for (int ks = 0; ks < 2; ++ks) {
            v8s af = *(const v8s*)&sa[cur][wv * 16 + r16][(((ks << 2) + g) ^ (r16 & 7)) << 3];
            v8s bf = *(const v8s*)&sc[r16][cn * 64 + ks * 32 + g * 8];
            acc = __builtin_amdgcn_mfma_f32_16x16x32_bf16(af, bf, acc, 0, 0, 0);
        }
        if (cn < 11) {
            *(v8s*)&sa[cur ^ 1][srow][sphys] = n0;
            *(v8s*)&sa[cur ^ 1][srow + 8][sphys] = n1;
        }
    }

    // epilogue: softmax per row; C/D layout: col = lane&15, row = g*4 + j
    float cx = scx[r16], cy = scy[r16], c2v = sc2[r16];
    #pragma unroll
    for (int j = 0; j < 4; ++j) {
        int p = pb * 64 + wv * 16 + g * 4 + j;
        float px = (float)(p % SGRID) * COMPF;
        float py = (float)(p / SGRID) * COMPF;
        float lg = 2.f * (acc[j] + px * cx + py * cy) - c2v;
        float mx = lg;
        mx = fmaxf(mx, __shfl_xor(mx, 1));
        mx = fmaxf(mx, __shfl_xor(mx, 2));
        mx = fmaxf(mx, __shfl_xor(mx, 4));
        mx = fmaxf(mx, __shfl_xor(mx, 8));
        float e = __expf(lg - mx);
        float se = e;
        se += __shfl_xor(se, 1);
        se += __shfl_xor(se, 2);
        se += __shfl_xor(se, 4);
        se += __shfl_xor(se, 8);
        if (r16 < NK)
            out[((size_t)b * NP + p) * ostride + r16] = e / se;
    }
}

// ---------------- update: partial centroid sums (bf16 emb, fp32 accum) ------
// grid NB*SUPD, 192 thr. Thread t owns channels 4t..4t+3. initMode: a = one-hot
// 8x8-pool indicator (reproduces SSN init exactly up to the eps division).
__global__ __launch_bounds__(192) void update_b(const unsigned short* __restrict__ embb,
                                                const float* __restrict__ abuf,
                                                float* __restrict__ pcent, int initMode)
{
    __shared__ float sa[PPB * 12];
    int b = blockIdx.x / SUPD, s = blockIdx.x % SUPD;
    int t = threadIdx.x, lane = t & 63, wv = t / 64;
    int p0 = s * PPB;

    if (!initMode) {
        const float4* ag = (const float4*)(abuf + ((size_t)b * NP + p0) * 12);
        for (int i = t; i < PPB * 3; i += 192) ((float4*)sa)[i] = ag[i];
    } else {
        for (int i = t; i < PPB * 12; i += 192) {
            int p = i / 12, k = i % 12;
            int pg = p0 + p;
            int kin = ((pg / SGRID) / 8) * 3 + (pg % SGRID) / 8;
            sa[i] = (k == kin) ? 1.0f : 0.0f;
        }
    }
    __syncthreads();

    float* pc = pcent + (size_t)(b * SUPD + s) * NK * 772;
    if (wv == 0) {
        #pragma unroll
        for (int k = 0; k < NK; ++k) {
            float w = 0.f, sx = 0.f, sy = 0.f;
            if (lane < PPB) {
                float av = sa[lane * 12 + k];
                int pg = p0 + lane;
                w = av;
                sx = av * (float)(pg % SGRID) * COMPF;
                sy = av * (float)(pg / SGRID) * COMPF;
            }
            #pragma unroll
            for (int m = 1; m < 64; m <<= 1) {
                w += __shfl_xor(w, m);
                sx += __shfl_xor(sx, m);
                sy += __shfl_xor(sy, m);
            }
            if (lane == 0) { pc[k * 772 + 770] = w; pc[k * 772 + 768] = sx; pc[k * 772 + 769] = sy; }
        }
    }

    float acc[NK][4];
    #pragma unroll
    for (int k = 0; k < NK; ++k)
        #pragma unroll
        for (int j = 0; j < 4; ++j) acc[k][j] = 0.f;

    const unsigned short* e = embb + ((size_t)b * NP + p0) * EMB + t * 4;
    #pragma unroll 4
    for (int p = 0; p < PPB; ++p) {
        ushort4 uv = *(const ushort4*)(e + (size_t)p * EMB);
        float f0 = b2f(uv.x), f1 = b2f(uv.y), f2 = b2f(uv.z), f3 = b2f(uv.w);
        const float* ar = &sa[p * 12];
        #pragma unroll
        for (int k = 0; k < NK; ++k) {
            float av = ar[k];
            acc[k][0] += av * f0; acc[k][1] += av * f1;
            acc[k][2] += av * f2; acc[k][3] += av * f3;
        }
    }
    #pragma unroll
    for (int k = 0; k < NK; ++k) {
        float4 v = make_float4(acc[k][0], acc[k][1], acc[k][2], acc[k][3]);
        *(float4*)&pc[k * 772 + t * 4] = v;
    }
}

// ---------------- reduce: combine partials -> bf16 centroids + c2 + csp -----
__global__ __launch_bounds__(256) void reduce_b(const float* __restrict__ pcent,
                                                unsigned short* __restrict__ centb,
                                                float* __restrict__ c2b,
                                                float* __restrict__ csp)
{
    __shared__ float sw9[NK], red[4 * NK];
    int b = blockIdx.x, t = threadIdx.x, lane = t & 63, wv = t >> 6;
    const float* pc = pcent + (size_t)b * SUPD * NK * 772;

    if (t < NK) {
        float w = 0.f, sx = 0.f, sy = 0.f;
        for (int s = 0; s < SUPD; ++s) {
            const float* q = pc + (size_t)(s * NK + t) * 772;
            w += q[770]; sx += q[768]; sy += q[769];
        }
        float wi = w + EPSV;
        sw9[t] = wi;
        csp[((size_t)b * NK + t) * 2 + 0] = sx / wi;
        csp[((size_t)b * NK + t) * 2 + 1] = sy / wi;
    }
    __syncthreads();

    float c2p[NK];
    #pragma unroll
    for (int k = 0; k < NK; ++k) c2p[k] = 0.f;
    #pragma unroll
    for (int j = 0; j < 3; ++j) {
        int c = t + j * 256;
        #pragma unroll
        for (int k = 0; k < NK; ++k) {
            float v = 0.f;
            for (int s = 0; s < SUPD; ++s) v += pc[(size_t)(s * NK + k) * 772 + c];
            float r = v / sw9[k];
            centb[((size_t)b * NK + k) * EMB + c] = f2b(r);
            c2p[k] += r * r;
        }
    }
    #pragma unroll
    for (int k = 0; k < NK; ++k) {
        float s = c2p[k];
        #pragma unroll
        for (int m = 1; m < 64; m <<= 1) s += __shfl_xor(s, m);
        if (lane == 0) red[wv * NK + k] = s;
    }
    __syncthreads();
    if (t < NK) {
        float c2 = red[t] + red[NK + t] + red[2 * NK + t] + red[3 * NK + t];
        float x = csp[((size_t)b * NK + t) * 2 + 0];
        float y = csp[((size_t)b * NK + t) * 2 + 1];
        c2b[b * 16 + t] = c2 + x * x + y * y;
    }
    if (t >= NK && t < 16) c2b[b * 16 + t] = 1e30f;
}

extern "C" void kernel_launch(void* const* d_in, const int* in_sizes, int n_in,
                              void* d_out, int out_size, void* d_ws, size_t ws_size,
                              hipStream_t stream) {
    const float* emb = (const float*)d_in[0];
    char* w = (char*)d_ws;
    unsigned short* embb = (unsigned short*)w;  w += (size_t)NB * NP * EMB * 2;        // 113.2 MB
    float* abuf  = (float*)w;                   w += (size_t)NB * NP * 12 * 4;         // 3.5 MB
    float* pcent = (float*)w;                   w += (size_t)NB * SUPD * NK * 772 * 4; // 42.7 MB
    unsigned short* centb = (unsigned short*)w; w += (size_t)NB * NK * EMB * 2;        // 1.8 MB
    float* c2b   = (float*)w;                   w += (size_t)NB * 16 * 4;
    float* csp   = (float*)w;                   w += (size_t)NB * NK * 2 * 4;

    conv_k<<<(NB * NP * EMB) / (256 * 8), 256, 0, stream>>>(emb, embb);

    update_b<<<NB * SUPD, 192, 0, stream>>>(embb, nullptr, pcent, 1);
    reduce_b<<<NB, 256, 0, stream>>>(pcent, centb, c2b, csp);

    for (int it = 0; it < NITER; ++it) {
        assign_mfma<<<NB * 9, 256, 0, stream>>>(embb, centb, c2b, csp, abuf, 12);
        update_b<<<NB * SUPD, 192, 0, stream>>>(embb, abuf, pcent, 0);
        reduce_b<<<NB, 256, 0, stream>>>(pcent, centb, c2b, csp);
    }
    assign_mfma<<<NB * 9, 256, 0, stream>>>(embb, centb, c2b, csp, (float*)d_out, 9);
}

// Round 3
// 733.776 us; speedup vs baseline: 3.2685x; 1.3979x over previous
//
#include <hip/hip_runtime.h>

#define NB 128
#define NP 576
#define NK 9
#define EMB 768
#define SGRID 24
#define COMPF 3.0f
#define NITER 10
#define EPSV 1e-8f
#define CSTR 772   // per-cluster stride in pcent: 768 ch + sx,sy,w,pad

typedef short v8s __attribute__((ext_vector_type(8)));
typedef float v4f __attribute__((ext_vector_type(4)));

__device__ __forceinline__ unsigned short f2b(float f) {
    unsigned x = __float_as_uint(f);
    unsigned r = (x + 0x7fffu + ((x >> 16) & 1u)) >> 16;
    return (unsigned short)r;
}
__device__ __forceinline__ float b2f(unsigned short u) {
    return __uint_as_float(((unsigned)u) << 16);
}

// ---------------- init: fp32->bf16 conversion + indicator partial sums ------
// grid NB*9, 192 thr. Block = one 64-point tile. Thread t owns channels 4t..4t+3.
// Within a tile, the seed-cluster row band ay = pb/3 is constant; only clusters
// ay*3 + {0,1,2} receive mass. Accumulates the ORIGINAL fp32 values (matches
// reference init pooling); writes bf16 emb for all later kernels.
__global__ __launch_bounds__(192) void init_k(const float* __restrict__ emb,
                                              unsigned short* __restrict__ embb,
                                              float* __restrict__ pcent) {
    int blk = blockIdx.x, b = blk / 9, pb = blk % 9;
    int t = threadIdx.x;
    int ay = pb / 3;

    float a0x=0,a0y=0,a0z=0,a0w=0, a1x=0,a1y=0,a1z=0,a1w=0, a2x=0,a2y=0,a2z=0,a2w=0;
    const float* eg = emb + ((size_t)b * NP + pb * 64) * EMB + t * 4;
    unsigned short* og = embb + ((size_t)b * NP + pb * 64) * EMB + t * 4;
    for (int p = 0; p < 64; ++p) {
        float4 f = *(const float4*)(eg + (size_t)p * EMB);
        ushort4 u;
        u.x = f2b(f.x); u.y = f2b(f.y); u.z = f2b(f.z); u.w = f2b(f.w);
        *(ushort4*)(og + (size_t)p * EMB) = u;
        int pg = pb * 64 + p;
        int sel = (pg % SGRID) >> 3;   // 0..2
        bool m0 = (sel == 0), m1 = (sel == 1), m2 = (sel == 2);
        a0x += m0 ? f.x : 0.f; a0y += m0 ? f.y : 0.f; a0z += m0 ? f.z : 0.f; a0w += m0 ? f.w : 0.f;
        a1x += m1 ? f.x : 0.f; a1y += m1 ? f.y : 0.f; a1z += m1 ? f.z : 0.f; a1w += m1 ? f.w : 0.f;
        a2x += m2 ? f.x : 0.f; a2y += m2 ? f.y : 0.f; a2z += m2 ? f.z : 0.f; a2w += m2 ? f.w : 0.f;
    }
    float* pc = pcent + (size_t)(b * 9 + pb) * NK * CSTR;
    #pragma unroll
    for (int k = 0; k < NK; ++k) {
        int s = k - ay * 3;
        float4 v = make_float4(0.f, 0.f, 0.f, 0.f);
        if (s == 0) v = make_float4(a0x, a0y, a0z, a0w);
        if (s == 1) v = make_float4(a1x, a1y, a1z, a1w);
        if (s == 2) v = make_float4(a2x, a2y, a2z, a2w);
        *(float4*)&pc[k * CSTR + t * 4] = v;
    }
    if (t < NK) {
        int s = t - ay * 3;
        float w = 0.f, sx = 0.f, sy = 0.f;
        if (s >= 0 && s < 3) {
            for (int p = 0; p < 64; ++p) {
                int pg = pb * 64 + p;
                if (((pg % SGRID) >> 3) == s) {
                    w += 1.f;
                    sx += (float)(pg % SGRID) * COMPF;
                    sy += (float)(pg / SGRID) * COMPF;
                }
            }
        }
        pc[t * CSTR + 768] = sx; pc[t * CSTR + 769] = sy; pc[t * CSTR + 770] = w;
    }
}

// ---------------- fused: assign (MFMA) + partial update ----------------
// grid NB*9, 256 thr (4 waves). Phase 1: logits via mfma_16x16x32_bf16 with
// double-buffered LDS A-tile; softmax in-register. Phase 2: per-tile partial
// centroid sums (update_b-style), emb re-read from global (L1/L2-hot).
__global__ __launch_bounds__(256) void fused_k(
    const unsigned short* __restrict__ embb,   // [NB][576][768] bf16
    const unsigned short* __restrict__ centb,  // [NB][9][768] bf16
    const float* __restrict__ csp,             // [NB][9][2]
    float* __restrict__ pcent,                 // [NB][9 tiles][NK][CSTR]
    float* __restrict__ out, int outMode)
{
    __shared__ unsigned short sc[16][776];     // B: [cluster][768 + pad8]
    __shared__ unsigned short sa[2][64][64];   // A dbuf, slice-swizzled
    __shared__ float scx[16], scy[16], sc2[16];
    __shared__ float sap[64][16];              // probs for phase 2
    __shared__ float red[4][3][16];            // [wave][{w,sx,sy}][k]

    int blk = blockIdx.x;
    int b = blk / 9, pb = blk % 9;
    int t = threadIdx.x, lane = t & 63, wv = t >> 6;
    int r16 = lane & 15, g = lane >> 4;

    // stage centroids (B operand), zero-pad clusters 9..15
    const unsigned short* cg = centb + (size_t)b * NK * EMB;
    for (int i = t; i < NK * 96; i += 256) {
        int k = i / 96, s = i % 96;
        *(v8s*)&sc[k][s * 8] = *(const v8s*)&cg[k * EMB + s * 8];
    }
    for (int i = t; i < 7 * 96; i += 256) {
        int k = 9 + i / 96, s = i % 96;
        v8s z = {0,0,0,0,0,0,0,0};
        *(v8s*)&sc[k][s * 8] = z;
    }
    if (t < 16) {
        scx[t] = (t < NK) ? csp[((size_t)b * NK + t) * 2 + 0] : 0.f;
        scy[t] = (t < NK) ? csp[((size_t)b * NK + t) * 2 + 1] : 0.f;
    }

    // first A chunk (issue before the barrier; stored after)
    const unsigned short* eg = embb + ((size_t)b * NP + pb * 64) * EMB;
    int srow = wv * 16 + (lane >> 3);
    int sphys = ((lane & 7) ^ (lane >> 3)) * 8;
    const unsigned short* gbase = eg + (size_t)srow * EMB + (lane & 7) * 8;
    v8s st0 = *(const v8s*)(gbase);
    v8s st1 = *(const v8s*)(gbase + 8 * EMB);

    __syncthreads();   // sc, scx/scy ready

    // c2 from the staged (bf16) centroids — wave 0
    if (wv == 0) {
        for (int k = 0; k < NK; ++k) {
            float s = 0.f;
            const unsigned short* ck = sc[k];
            for (int c = lane; c < EMB; c += 64) { float v = b2f(ck[c]); s += v * v; }
            #pragma unroll
            for (int m = 1; m < 64; m <<= 1) s += __shfl_xor(s, m);
            if (lane == 0) sc2[k] = s + scx[k] * scx[k] + scy[k] * scy[k];
        }
        if (lane >= NK && lane < 16) sc2[lane] = 1e30f;
    }

    *(v8s*)&sa[0][srow][sphys] = st0;
    *(v8s*)&sa[0][srow + 8][sphys] = st1;

    v4f acc = {0.f, 0.f, 0.f, 0.f};
    for (int cn = 0; cn < 12; ++cn) {
        v8s n0, n1;
        if (cn < 11) {
            n0 = *(const v8s*)(gbase + (cn + 1) * 64);
            n1 = *(const v8s*)(gbase + (cn + 1) * 64 + 8 * EMB);
        }
        __syncthreads();
        int cur = cn & 1;
        #pragma unroll
        for (int ks = 0; ks < 2; ++ks) {
            v8s af = *(const v8s*)&sa[cur][wv * 16 + r16][(((ks << 2) + g) ^ (r16 & 7)) << 3];
            v8s bf = *(const v8s*)&sc[r16][cn * 64 + ks * 32 + g * 8];
            acc = __builtin_amdgcn_mfma_f32_16x16x32_bf16(af, bf, acc, 0, 0, 0);
        }
        if (cn < 11) {
            *(v8s*)&sa[cur ^ 1][srow][sphys] = n0;
            *(v8s*)&sa[cur ^ 1][srow + 8][sphys] = n1;
        }
    }

    // epilogue: softmax per row; C/D: col = r16, row = g*4 + j
    float cx = scx[r16], cy = scy[r16], c2v = sc2[r16];
    float wsum = 0.f, sxsum = 0.f, sysum = 0.f;
    #pragma unroll
    for (int j = 0; j < 4; ++j) {
        int row = wv * 16 + g * 4 + j;
        int p = pb * 64 + row;
        float px = (float)(p % SGRID) * COMPF;
        float py = (float)(p / SGRID) * COMPF;
        float lg = 2.f * (acc[j] + px * cx + py * cy) - c2v;
        float mx = lg;
        mx = fmaxf(mx, __shfl_xor(mx, 1));
        mx = fmaxf(mx, __shfl_xor(mx, 2));
        mx = fmaxf(mx, __shfl_xor(mx, 4));
        mx = fmaxf(mx, __shfl_xor(mx, 8));
        float e = __expf(lg - mx);
        float se = e;
        se += __shfl_xor(se, 1);
        se += __shfl_xor(se, 2);
        se += __shfl_xor(se, 4);
        se += __shfl_xor(se, 8);
        float prob = e / se;
        if (outMode) {
            if (r16 < NK) out[((size_t)b * NP + p) * NK + r16] = prob;
        } else {
            if (r16 < NK) sap[row][r16] = prob;
            wsum += prob;
            sxsum += prob * px;
            sysum += prob * py;
        }
    }
    if (outMode) return;

    wsum  += __shfl_xor(wsum, 16);  wsum  += __shfl_xor(wsum, 32);
    sxsum += __shfl_xor(sxsum, 16); sxsum += __shfl_xor(sxsum, 32);
    sysum += __shfl_xor(sysum, 16); sysum += __shfl_xor(sysum, 32);
    if (lane < 16) {
        red[wv][0][r16] = wsum;
        red[wv][1][r16] = sxsum;
        red[wv][2][r16] = sysum;
    }
    __syncthreads();   // sap + red ready

    float* pc = pcent + (size_t)(b * 9 + pb) * NK * CSTR;
    if (t < NK) {
        pc[t * CSTR + 770] = red[0][0][t] + red[1][0][t] + red[2][0][t] + red[3][0][t];
        pc[t * CSTR + 768] = red[0][1][t] + red[1][1][t] + red[2][1][t] + red[3][1][t];
        pc[t * CSTR + 769] = red[0][2][t] + red[1][2][t] + red[2][2][t] + red[3][2][t];
    }

    // phase 2: partial centroid sums. Thread t<192 owns channels 4t..4t+3.
    if (t < 192) {
        float a2[NK][4];
        #pragma unroll
        for (int k = 0; k < NK; ++k)
            #pragma unroll
            for (int j = 0; j < 4; ++j) a2[k][j] = 0.f;
        const unsigned short* e2 = eg + t * 4;
        #pragma unroll 4
        for (int p = 0; p < 64; ++p) {
            ushort4 uv = *(const ushort4*)(e2 + (size_t)p * EMB);
            float f0 = b2f(uv.x), f1 = b2f(uv.y), f2v = b2f(uv.z), f3 = b2f(uv.w);
            const float* ar = sap[p];
            #pragma unroll
            for (int k = 0; k < NK; ++k) {
                float av = ar[k];
                a2[k][0] += av * f0; a2[k][1] += av * f1;
                a2[k][2] += av * f2v; a2[k][3] += av * f3;
            }
        }
        #pragma unroll
        for (int k = 0; k < NK; ++k)
            *(float4*)&pc[k * CSTR + t * 4] =
                make_float4(a2[k][0], a2[k][1], a2[k][2], a2[k][3]);
    }
}

// ---------------- reduce: 9 partials -> bf16 centroids + csp ----------------
// grid NB*3; block cb handles channels cb*256 + t. w computed redundantly.
__global__ __launch_bounds__(256) void reduce_k(const float* __restrict__ pcent,
                                                unsigned short* __restrict__ centb,
                                                float* __restrict__ csp) {
    __shared__ float sw[NK];
    int b = blockIdx.x / 3, cb = blockIdx.x % 3;
    int t = threadIdx.x;
    const float* pc = pcent + (size_t)b * 9 * NK * CSTR;

    if (t < NK) {
        float w = 0.f, sx = 0.f, sy = 0.f;
        for (int s = 0; s < 9; ++s) {
            const float* q = pc + (size_t)(s * NK + t) * CSTR;
            sx += q[768]; sy += q[769]; w += q[770];
        }
        float wi = w + EPSV;
        sw[t] = wi;
        if (cb == 0) {
            csp[((size_t)b * NK + t) * 2 + 0] = sx / wi;
            csp[((size_t)b * NK + t) * 2 + 1] = sy / wi;
        }
    }
    __syncthreads();

    int c = cb * 256 + t;
    #pragma unroll
    for (int k = 0; k < NK; ++k) {
        float v = 0.f;
        #pragma unroll
        for (int s = 0; s < 9; ++s) v += pc[(size_t)(s * NK + k) * CSTR + c];
        centb[((size_t)b * NK + k) * EMB + c] = f2b(v / sw[k]);
    }
}

extern "C" void kernel_launch(void* const* d_in, const int* in_sizes, int n_in,
                              void* d_out, int out_size, void* d_ws, size_t ws_size,
                              hipStream_t stream) {
    const float* emb = (const float*)d_in[0];
    char* w = (char*)d_ws;
    unsigned short* embb = (unsigned short*)w;  w += (size_t)NB * NP * EMB * 2;          // 113.2 MB
    float* pcent = (float*)w;                   w += (size_t)NB * 9 * NK * CSTR * 4;     // 32.0 MB
    unsigned short* centb = (unsigned short*)w; w += (size_t)NB * NK * EMB * 2;          // 1.8 MB
    float* csp = (float*)w;                     w += (size_t)NB * NK * 2 * 4;

    init_k<<<NB * 9, 192, 0, stream>>>(emb, embb, pcent);
    reduce_k<<<NB * 3, 256, 0, stream>>>(pcent, centb, csp);

    for (int it = 0; it < NITER; ++it) {
        fused_k<<<NB * 9, 256, 0, stream>>>(embb, centb, csp, pcent, nullptr, 0);
        reduce_k<<<NB * 3, 256, 0, stream>>>(pcent, centb, csp);
    }
    fused_k<<<NB * 9, 256, 0, stream>>>(embb, centb, csp, pcent, (float*)d_out, 1);
}